// Round 2
// baseline (473.204 us; speedup 1.0000x reference)
//
#include <hip/hip_runtime.h>
#include <stdint.h>

// Output layout (float32 elements within d_out):
//   q_out : [8][1024][64][64]  at offset 0          (33,554,432)
//   code  : [8][4][64][64]     at offset 33,554,432 (131,072)  -- stored as float
//   logit : [8][1024][64][64]  at offset 33,685,504 (33,554,432)
#define CODE_OFF  33554432u
#define LOGIT_OFF 33685504u

__device__ __forceinline__ uint32_t rotl32(uint32_t x, int r) {
  return (x << r) | (x >> (32 - r));
}

// Partitionable threefry (JAX >= 0.4.36 default): per-element 64-bit counter
// = row-major flat index i; counter words (x0,x1) = (i>>32, i&0xffffffff) =
// (0, i) here since size = 2^25. key = (0, 42). 32-bit draw = o0 ^ o1.
// Schedule matches JAX threefry_2x32: initial inject ks0/ks1, 5 groups of 4
// rounds, rotations [13,15,26,6]/[17,29,16,24], rotating key injection.
__device__ __forceinline__ uint32_t tf32_part(uint32_t i) {
  const uint32_t ks1 = 42u;
  const uint32_t ks2 = 0x1BD11BDAu ^ 42u;  // ks0 = 0
  uint32_t x0 = 0u;          // hi word + ks0(=0)
  uint32_t x1 = i + ks1;     // lo word + ks1
#define R4(a,b,c,d) \
  x0 += x1; x1 = rotl32(x1,(a)); x1 ^= x0; \
  x0 += x1; x1 = rotl32(x1,(b)); x1 ^= x0; \
  x0 += x1; x1 = rotl32(x1,(c)); x1 ^= x0; \
  x0 += x1; x1 = rotl32(x1,(d)); x1 ^= x0;
  R4(13,15,26,6)   x0 += ks1; x1 += ks2 + 1u;
  R4(17,29,16,24)  x0 += ks2; x1 += 2u;          // + ks0(=0) + 2
  R4(13,15,26,6)               x1 += ks1 + 3u;   // x0 += ks0(=0)
  R4(17,29,16,24)  x0 += ks1; x1 += ks2 + 4u;
  R4(13,15,26,6)   x0 += ks2; x1 += 5u;          // + ks0(=0) + 5
#undef R4
  return x0 ^ x1;
}

// JAX uniform(minval=tiny, maxval=1): u = bitcast(bits>>9 | 0x3f800000) - 1,
// clamped to tiny when zero; gumbel = -log(-log(u)).
__device__ __forceinline__ float bits_to_gumbel(uint32_t bits) {
  uint32_t fb = (bits >> 9) | 0x3f800000u;
  float f = __uint_as_float(fb) - 1.0f;
  float u = (f > 0.0f) ? f : 1.17549435e-38f;
  return -logf(-logf(u));
}

// Block: 256 threads = (tx in [0,16) -> 2 hw positions each; ty in [0,16) ->
// 16 k's as k = j*64 + ty*4 + d). Each block covers one (n<4, m), a 32-wide
// hw tile, and BOTH n-halves (n and n+4) to amortize w staging.
__global__ __launch_bounds__(256, 4)
void mcq_kernel(const float* __restrict__ x, const float* __restrict__ w,
                float* __restrict__ out) {
  __shared__ float x_lds[4096];  // [c][pos*2 + half], c in [0,64), pos in [0,32)
  __shared__ float w_lds[4096];  // [cc][k], cc in [0,16) chunk of c, k in [0,256)

  const int tid = threadIdx.x;
  const int tx = tid & 15;
  const int ty = tid >> 4;
  const int bid = blockIdx.x;
  const int nm = bid >> 7;    // 0..15 : n = nm>>2 in [0,4), m = nm&3
  const int tile = bid & 127; // 0..127
  const int hw0 = tile * 32;
  const int n = nm >> 2;
  const int m = nm & 3;

  float* q_out = out;
  float* code_out = out + CODE_OFF;
  float* logit_out = out + LOGIT_OFF;

  // ---- stage x for both n-halves, interleaved by half ----
  {
    const float* xA = x + ((size_t)(n * 256 + m * 64)) * 4096 + hw0;
    const float* xB = x + ((size_t)((n + 4) * 256 + m * 64)) * 4096 + hw0;
#pragma unroll
    for (int it = 0; it < 16; ++it) {
      int idx = tid + it * 256;      // 0..4095
      int c = idx >> 6;
      int rem = idx & 63;            // pos*2 + half
      int pos = rem >> 1;
      const float* src = (rem & 1) ? xB : xA;
      x_lds[idx] = src[(size_t)c * 4096 + pos];
    }
  }

  // accumulators: [half A/B][p 0/1][16 k-slots]; jd -> k = (jd>>2)*64 + ty*4 + (jd&3)
  float accA0[16], accB0[16], accA1[16], accB1[16];
#pragma unroll
  for (int i = 0; i < 16; ++i) accA0[i] = accB0[i] = accA1[i] = accB1[i] = 0.0f;

  const float* wrow = w + (size_t)m * 256 * 64;  // w[m][k][c], c contiguous

  for (int chunk = 0; chunk < 4; ++chunk) {
    __syncthreads();  // previous chunk's compute done before overwriting w_lds
    {
      // thread 'tid' owns k=tid: read 16 c's, write transposed [cc][k]
      const float* wk = wrow + tid * 64 + chunk * 16;
#pragma unroll
      for (int q = 0; q < 4; ++q) {
        float4 v = *(const float4*)(wk + q * 4);
        w_lds[(q * 4 + 0) * 256 + tid] = v.x;
        w_lds[(q * 4 + 1) * 256 + tid] = v.y;
        w_lds[(q * 4 + 2) * 256 + tid] = v.z;
        w_lds[(q * 4 + 3) * 256 + tid] = v.w;
      }
    }
    __syncthreads();
#pragma unroll
    for (int cc = 0; cc < 16; ++cc) {
      int c = chunk * 16 + cc;
      // {A p0, B p0, A p1, B p1}
      float4 xv = *(const float4*)&x_lds[c * 64 + tx * 4];
      float wv[16];
      *(float4*)&wv[0]  = *(const float4*)&w_lds[cc * 256 +   0 + ty * 4];
      *(float4*)&wv[4]  = *(const float4*)&w_lds[cc * 256 +  64 + ty * 4];
      *(float4*)&wv[8]  = *(const float4*)&w_lds[cc * 256 + 128 + ty * 4];
      *(float4*)&wv[12] = *(const float4*)&w_lds[cc * 256 + 192 + ty * 4];
#pragma unroll
      for (int jd = 0; jd < 16; ++jd) {
        float wkv = wv[jd];
        accA0[jd] += xv.x * wkv;
        accB0[jd] += xv.y * wkv;
        accA1[jd] += xv.z * wkv;
        accB1[jd] += xv.w * wkv;
      }
    }
  }

  // ---- epilogue: logit stores + gumbel + per-thread argmax (k ascending) ----
  float bestA0 = -3.4e38f, bestB0 = -3.4e38f, bestA1 = -3.4e38f, bestB1 = -3.4e38f;
  int iA0 = 0, iB0 = 0, iA1 = 0, iB1 = 0;
  // flat index base: elem(n<4 half) = nm*2^20 + hw*256 + k ; half B adds 16*2^20
  const uint32_t baseA0 = ((uint32_t)(nm * 4096 + hw0 + tx * 2)) << 8;      // p0, half A
  const uint32_t baseA1 = baseA0 + 256u;                                     // p1, half A
  const uint32_t baseB0 = baseA0 + (16u << 20);                              // p0, half B
  const uint32_t baseB1 = baseB0 + 256u;                                     // p1, half B
#pragma unroll
  for (int jd = 0; jd < 16; ++jd) {
    int k = (jd >> 2) * 64 + ty * 4 + (jd & 3);
    size_t offA = (size_t)(nm * 256 + k) * 4096 + hw0 + tx * 2;
    size_t offB = (size_t)((nm + 16) * 256 + k) * 4096 + hw0 + tx * 2;
    *(float2*)(logit_out + offA) = make_float2(accA0[jd], accA1[jd]);
    *(float2*)(logit_out + offB) = make_float2(accB0[jd], accB1[jd]);
    uint32_t bA0 = tf32_part(baseA0 + (uint32_t)k);
    uint32_t bA1 = tf32_part(baseA1 + (uint32_t)k);
    uint32_t bB0 = tf32_part(baseB0 + (uint32_t)k);
    uint32_t bB1 = tf32_part(baseB1 + (uint32_t)k);
    float vA0 = bits_to_gumbel(bA0) + accA0[jd];
    float vA1 = bits_to_gumbel(bA1) + accA1[jd];
    float vB0 = bits_to_gumbel(bB0) + accB0[jd];
    float vB1 = bits_to_gumbel(bB1) + accB1[jd];
    if (vA0 > bestA0) { bestA0 = vA0; iA0 = k; }
    if (vB0 > bestB0) { bestB0 = vB0; iB0 = k; }
    if (vA1 > bestA1) { bestA1 = vA1; iA1 = k; }
    if (vB1 > bestB1) { bestB1 = vB1; iB1 = k; }
  }

  // ---- cross-thread argmax reduction over the 16 k-owners (ty) ----
  __syncthreads();  // all compute reads of w_lds done; reuse it
  float* red_val = w_lds;               // [64 slots][17]
  int* red_idx = (int*)(w_lds + 1088);  // [64 slots][17]
  {
    int pos0 = tx * 2;
    red_val[(pos0 * 2 + 0) * 17 + ty] = bestA0;  red_idx[(pos0 * 2 + 0) * 17 + ty] = iA0;
    red_val[(pos0 * 2 + 1) * 17 + ty] = bestB0;  red_idx[(pos0 * 2 + 1) * 17 + ty] = iB0;
    red_val[((pos0 + 1) * 2 + 0) * 17 + ty] = bestA1; red_idx[((pos0 + 1) * 2 + 0) * 17 + ty] = iA1;
    red_val[((pos0 + 1) * 2 + 1) * 17 + ty] = bestB1; red_idx[((pos0 + 1) * 2 + 1) * 17 + ty] = iB1;
  }
  __syncthreads();
  int* idx_final = (int*)x_lds;  // 64 ints; x_lds no longer needed
  if (tid < 64) {
    float bv = -3.4e38f; int bi = 0x7fffffff;
#pragma unroll
    for (int t2 = 0; t2 < 16; ++t2) {
      float v = red_val[tid * 17 + t2];
      int ix = red_idx[tid * 17 + t2];
      // tie -> smallest k (jnp.argmax first-occurrence semantics)
      if (v > bv || (v == bv && ix < bi)) { bv = v; bi = ix; }
    }
    idx_final[tid] = bi;
    int pos = tid >> 1;
    int half = tid & 1;
    code_out[(size_t)(nm + (half ? 16 : 0)) * 4096 + hw0 + pos] = (float)bi;
  }
  __syncthreads();

  // ---- one-hot q_out (race-free: every k written by its owner thread) ----
  const int fA0 = idx_final[(tx * 2) * 2 + 0];
  const int fB0 = idx_final[(tx * 2) * 2 + 1];
  const int fA1 = idx_final[(tx * 2 + 1) * 2 + 0];
  const int fB1 = idx_final[(tx * 2 + 1) * 2 + 1];
#pragma unroll
  for (int jd = 0; jd < 16; ++jd) {
    int k = (jd >> 2) * 64 + ty * 4 + (jd & 3);
    size_t offA = (size_t)(nm * 256 + k) * 4096 + hw0 + tx * 2;
    size_t offB = (size_t)((nm + 16) * 256 + k) * 4096 + hw0 + tx * 2;
    *(float2*)(q_out + offA) = make_float2(k == fA0 ? 1.0f : 0.0f, k == fA1 ? 1.0f : 0.0f);
    *(float2*)(q_out + offB) = make_float2(k == fB0 ? 1.0f : 0.0f, k == fB1 ? 1.0f : 0.0f);
  }
}

extern "C" void kernel_launch(void* const* d_in, const int* in_sizes, int n_in,
                              void* d_out, int out_size, void* d_ws, size_t ws_size,
                              hipStream_t stream) {
  const float* x = (const float*)d_in[0];  // [8][256][64][64] fp32
  const float* w = (const float*)d_in[1];  // [4][256][64] fp32
  float* out = (float*)d_out;
  mcq_kernel<<<dim3(2048), dim3(256), 0, stream>>>(x, w, out);
}

// Round 3
// 395.964 us; speedup vs baseline: 1.1951x; 1.1951x over previous
//
#include <hip/hip_runtime.h>
#include <stdint.h>

// Output layout (float32 elements within d_out):
//   q_out : [8][1024][64][64]  at offset 0          (33,554,432)
//   code  : [8][4][64][64]     at offset 33,554,432 (131,072)  -- stored as float
//   logit : [8][1024][64][64]  at offset 33,685,504 (33,554,432)
#define CODE_OFF  33554432u
#define LOGIT_OFF 33685504u

typedef __attribute__((address_space(1))) const void g_void;
typedef __attribute__((address_space(3))) void l_void;

__device__ __forceinline__ uint32_t rotl32(uint32_t x, int r) {
  return (x << r) | (x >> (32 - r));
}

// Partitionable threefry (JAX >= 0.4.36 default): counter words (0, flat_idx),
// key (0,42), 20 rounds, draw = o0 ^ o1. Verified bit-exact in round 2.
__device__ __forceinline__ uint32_t tf32_part(uint32_t i) {
  const uint32_t ks1 = 42u;
  const uint32_t ks2 = 0x1BD11BDAu ^ 42u;  // ks0 = 0
  uint32_t x0 = 0u;
  uint32_t x1 = i + ks1;
#define R4(a,b,c,d) \
  x0 += x1; x1 = rotl32(x1,(a)); x1 ^= x0; \
  x0 += x1; x1 = rotl32(x1,(b)); x1 ^= x0; \
  x0 += x1; x1 = rotl32(x1,(c)); x1 ^= x0; \
  x0 += x1; x1 = rotl32(x1,(d)); x1 ^= x0;
  R4(13,15,26,6)   x0 += ks1; x1 += ks2 + 1u;
  R4(17,29,16,24)  x0 += ks2; x1 += 2u;
  R4(13,15,26,6)               x1 += ks1 + 3u;
  R4(17,29,16,24)  x0 += ks1; x1 += ks2 + 4u;
  R4(13,15,26,6)   x0 += ks2; x1 += 5u;
#undef R4
  return x0 ^ x1;
}

__device__ __forceinline__ float bits_to_gumbel(uint32_t bits) {
  uint32_t fb = (bits >> 9) | 0x3f800000u;
  float f = __uint_as_float(fb) - 1.0f;
  float u = (f > 0.0f) ? f : 1.17549435e-38f;
  return -logf(-logf(u));
}

// Block: 256 threads. tx = tid&15: half = tx>>3 (n vs n+4), px = tx&7 ->
// 4 consecutive hw positions hw0 + 4*px + p. ty = tid>>4: 16 k's as
// k = j*64 + ty*4 + d. Each block: one (n<4, m), 32-wide hw tile, both halves.
__global__ __launch_bounds__(256, 4)
void mcq_kernel(const float* __restrict__ x, const float* __restrict__ w,
                float* __restrict__ out) {
  __shared__ __align__(16) float x_lds[4096];  // [c][half*32 + pos]
  __shared__ __align__(16) float w_lds[4096];  // [cc][k], cc = 16-c chunk

  const int tid = threadIdx.x;
  const int tx = tid & 15;
  const int ty = tid >> 4;
  const int half = tx >> 3;
  const int px = tx & 7;
  const int bid = blockIdx.x;
  const int nm = bid >> 7;    // n = nm>>2, m = nm&3
  const int tile = bid & 127;
  const int hw0 = tile * 32;
  const int n = nm >> 2;
  const int m = nm & 3;

  float* q_out = out;
  float* code_out = out + CODE_OFF;
  float* logit_out = out + LOGIT_OFF;

  // ---- stage x via global_load_lds (width 16); layout [c][half][pos] ----
  {
    const float* xA = x + (size_t)(n * 256 + m * 64) * 4096 + hw0;
    const float* xB = xA + (size_t)4 * 256 * 4096;
#pragma unroll
    for (int it = 0; it < 4; ++it) {
      int idx = it * 256 + tid;        // float4 slot, 0..1023
      int c = idx >> 4;
      int hs = (idx >> 3) & 1;
      int ck = idx & 7;
      const float* src = (hs ? xB : xA) + (size_t)c * 4096 + ck * 4;
      // wave-uniform LDS base; HW scatters lane*16
      float* dst = x_lds + ((it * 256 + (tid & ~63)) << 2);
      __builtin_amdgcn_global_load_lds((g_void*)src, (l_void*)dst, 16, 0, 0);
    }
  }

  const float* wrow = w + (size_t)m * 256 * 64;  // w[m][k][c], c contiguous
  float4 wr0, wr1, wr2, wr3;
  {  // chunk 0 of w into regs, then transposed to LDS
    const float* wk = wrow + tid * 64;
    wr0 = *(const float4*)(wk + 0);
    wr1 = *(const float4*)(wk + 4);
    wr2 = *(const float4*)(wk + 8);
    wr3 = *(const float4*)(wk + 12);
    w_lds[ 0 * 256 + tid] = wr0.x; w_lds[ 1 * 256 + tid] = wr0.y;
    w_lds[ 2 * 256 + tid] = wr0.z; w_lds[ 3 * 256 + tid] = wr0.w;
    w_lds[ 4 * 256 + tid] = wr1.x; w_lds[ 5 * 256 + tid] = wr1.y;
    w_lds[ 6 * 256 + tid] = wr1.z; w_lds[ 7 * 256 + tid] = wr1.w;
    w_lds[ 8 * 256 + tid] = wr2.x; w_lds[ 9 * 256 + tid] = wr2.y;
    w_lds[10 * 256 + tid] = wr2.z; w_lds[11 * 256 + tid] = wr2.w;
    w_lds[12 * 256 + tid] = wr3.x; w_lds[13 * 256 + tid] = wr3.y;
    w_lds[14 * 256 + tid] = wr3.z; w_lds[15 * 256 + tid] = wr3.w;
  }
  __syncthreads();  // drains x's lds-loads (vmcnt) + w writes

  // accumulators: acc{p}[jd], p = position offset 0..3 of this thread's half
  float acc0[16], acc1[16], acc2[16], acc3[16];
#pragma unroll
  for (int i = 0; i < 16; ++i) acc0[i] = acc1[i] = acc2[i] = acc3[i] = 0.0f;

#pragma unroll
  for (int chunk = 0; chunk < 4; ++chunk) {
    if (chunk < 3) {  // prefetch next w chunk into regs (retires under compute)
      const float* wk = wrow + tid * 64 + (chunk + 1) * 16;
      wr0 = *(const float4*)(wk + 0);
      wr1 = *(const float4*)(wk + 4);
      wr2 = *(const float4*)(wk + 8);
      wr3 = *(const float4*)(wk + 12);
    }
#pragma unroll
    for (int cc = 0; cc < 16; ++cc) {
      int c = chunk * 16 + cc;
      float4 xv = *(const float4*)&x_lds[c * 64 + half * 32 + px * 4];
      float wv[16];
      *(float4*)&wv[0]  = *(const float4*)&w_lds[cc * 256 +   0 + ty * 4];
      *(float4*)&wv[4]  = *(const float4*)&w_lds[cc * 256 +  64 + ty * 4];
      *(float4*)&wv[8]  = *(const float4*)&w_lds[cc * 256 + 128 + ty * 4];
      *(float4*)&wv[12] = *(const float4*)&w_lds[cc * 256 + 192 + ty * 4];
#pragma unroll
      for (int jd = 0; jd < 16; ++jd) {
        float wkv = wv[jd];
        acc0[jd] += xv.x * wkv;
        acc1[jd] += xv.y * wkv;
        acc2[jd] += xv.z * wkv;
        acc3[jd] += xv.w * wkv;
      }
    }
    if (chunk < 3) {
      __syncthreads();  // compute on w_lds done
      w_lds[ 0 * 256 + tid] = wr0.x; w_lds[ 1 * 256 + tid] = wr0.y;
      w_lds[ 2 * 256 + tid] = wr0.z; w_lds[ 3 * 256 + tid] = wr0.w;
      w_lds[ 4 * 256 + tid] = wr1.x; w_lds[ 5 * 256 + tid] = wr1.y;
      w_lds[ 6 * 256 + tid] = wr1.z; w_lds[ 7 * 256 + tid] = wr1.w;
      w_lds[ 8 * 256 + tid] = wr2.x; w_lds[ 9 * 256 + tid] = wr2.y;
      w_lds[10 * 256 + tid] = wr2.z; w_lds[11 * 256 + tid] = wr2.w;
      w_lds[12 * 256 + tid] = wr3.x; w_lds[13 * 256 + tid] = wr3.y;
      w_lds[14 * 256 + tid] = wr3.z; w_lds[15 * 256 + tid] = wr3.w;
      __syncthreads();
    }
  }

  // ---- epilogue: float4 logit stores + gumbel + per-thread argmax ----
  float best0 = -3.4e38f, best1 = -3.4e38f, best2 = -3.4e38f, best3 = -3.4e38f;
  int i0 = 0, i1 = 0, i2 = 0, i3 = 0;
  // flat index = ((nm + 16*half)*4096 + hw) * 256 + k, hw = hw0 + 4*px + p
  const uint32_t base0 = ((uint32_t)((nm + 16 * half) * 4096 + hw0 + 4 * px)) << 8;
  const size_t row_off = (size_t)hw0 + 4 * px;
#pragma unroll
  for (int jd = 0; jd < 16; ++jd) {
    int k = (jd >> 2) * 64 + ty * 4 + (jd & 3);
    size_t off = (size_t)((nm + 16 * half) * 256 + k) * 4096 + row_off;
    *(float4*)(logit_out + off) = make_float4(acc0[jd], acc1[jd], acc2[jd], acc3[jd]);
    uint32_t b0 = tf32_part(base0 + 0u * 256u + (uint32_t)k);
    uint32_t b1 = tf32_part(base0 + 1u * 256u + (uint32_t)k);
    uint32_t b2 = tf32_part(base0 + 2u * 256u + (uint32_t)k);
    uint32_t b3 = tf32_part(base0 + 3u * 256u + (uint32_t)k);
    float v0 = bits_to_gumbel(b0) + acc0[jd];
    float v1 = bits_to_gumbel(b1) + acc1[jd];
    float v2 = bits_to_gumbel(b2) + acc2[jd];
    float v3 = bits_to_gumbel(b3) + acc3[jd];
    if (v0 > best0) { best0 = v0; i0 = k; }
    if (v1 > best1) { best1 = v1; i1 = k; }
    if (v2 > best2) { best2 = v2; i2 = k; }
    if (v3 > best3) { best3 = v3; i3 = k; }
  }

  // ---- cross-thread argmax reduction over the 16 k-owners (ty) ----
  __syncthreads();  // all compute reads of w_lds done; reuse it
  float* red_val = w_lds;               // [64 slots][17]
  int* red_idx = (int*)(w_lds + 1088);  // [64 slots][17]
  {
    int slot = half * 32 + px * 4;      // slot = half*32 + pos_local
    red_val[(slot + 0) * 17 + ty] = best0;  red_idx[(slot + 0) * 17 + ty] = i0;
    red_val[(slot + 1) * 17 + ty] = best1;  red_idx[(slot + 1) * 17 + ty] = i1;
    red_val[(slot + 2) * 17 + ty] = best2;  red_idx[(slot + 2) * 17 + ty] = i2;
    red_val[(slot + 3) * 17 + ty] = best3;  red_idx[(slot + 3) * 17 + ty] = i3;
  }
  __syncthreads();
  int* idx_final = (int*)x_lds;  // 64 ints; x_lds no longer needed
  if (tid < 64) {
    float bv = -3.4e38f; int bi = 0x7fffffff;
#pragma unroll
    for (int t2 = 0; t2 < 16; ++t2) {
      float v = red_val[tid * 17 + t2];
      int ix = red_idx[tid * 17 + t2];
      if (v > bv || (v == bv && ix < bi)) { bv = v; bi = ix; }  // tie -> smallest k
    }
    idx_final[tid] = bi;
    int h = tid >> 5;
    int pos = tid & 31;
    code_out[(size_t)(nm + 16 * h) * 4096 + hw0 + pos] = (float)bi;
  }
  __syncthreads();

  // ---- one-hot q_out (race-free: every k written by its owner thread) ----
  const int f0 = idx_final[half * 32 + px * 4 + 0];
  const int f1 = idx_final[half * 32 + px * 4 + 1];
  const int f2 = idx_final[half * 32 + px * 4 + 2];
  const int f3 = idx_final[half * 32 + px * 4 + 3];
#pragma unroll
  for (int jd = 0; jd < 16; ++jd) {
    int k = (jd >> 2) * 64 + ty * 4 + (jd & 3);
    size_t off = (size_t)((nm + 16 * half) * 256 + k) * 4096 + row_off;
    *(float4*)(q_out + off) = make_float4(k == f0 ? 1.0f : 0.0f, k == f1 ? 1.0f : 0.0f,
                                          k == f2 ? 1.0f : 0.0f, k == f3 ? 1.0f : 0.0f);
  }
}

extern "C" void kernel_launch(void* const* d_in, const int* in_sizes, int n_in,
                              void* d_out, int out_size, void* d_ws, size_t ws_size,
                              hipStream_t stream) {
  const float* x = (const float*)d_in[0];  // [8][256][64][64] fp32
  const float* w = (const float*)d_in[1];  // [4][256][64] fp32
  float* out = (float*)d_out;
  mcq_kernel<<<dim3(2048), dim3(256), 0, stream>>>(x, w, out);
}